// Round 8
// baseline (257.392 us; speedup 1.0000x reference)
//
#include <hip/hip_runtime.h>
#include <hip/hip_bf16.h>
#include <math.h>

// Problem constants
#define B_SZ   64
#define N_SZ   1024
#define M_SZ   4096
#define HID_SZ 2048
#define OUT_SZ 512

#define AS1 __attribute__((address_space(1)))
#define AS3 __attribute__((address_space(3)))

// ---------------------------------------------------------------------------
// Kernel 1: pairwise min-distance (unchanged; correctness-proven).
// ---------------------------------------------------------------------------
__global__ __launch_bounds__(256, 2) void dist_min_kernel(
    const float* __restrict__ pos,    // [B*N][3]
    const float* __restrict__ basis,  // [M][3]
    float* __restrict__ xT)           // [N][B]
{
  const int tid  = threadIdx.x;
  const int lane = tid & 63;
  const int wave = tid >> 6;

  float nqx[16], nqy[16], nqz[16], qc[16];
#pragma unroll
  for (int i = 0; i < 16; ++i) {
    int j = wave * 1024 + i * 64 + lane;
    float qx = basis[3*j+0], qy = basis[3*j+1], qz = basis[3*j+2];
    nqx[i] = -qx; nqy[i] = -qy; nqz[i] = -qz;
    qc[i]  = 0.5f * (qx*qx + qy*qy + qz*qz);
  }

  __shared__ float red[16][256];
  const int pbase = blockIdx.x * 128;

  for (int c = 0; c < 8; ++c) {
    const int cbase = pbase + c * 16;
    const float* pp = pos + (size_t)3 * cbase;
    float pc[48];
#pragma unroll
    for (int e = 0; e < 48; ++e) pc[e] = pp[e];

#pragma unroll   // FULL unroll (rule #20)
    for (int p = 0; p < 16; ++p) {
      const float px = pc[3*p+0], py = pc[3*p+1], pz = pc[3*p+2];
      float t[16];
#pragma unroll
      for (int i = 0; i < 16; ++i) t[i] = fmaf(nqx[i], px, qc[i]);
#pragma unroll
      for (int i = 0; i < 16; ++i) t[i] = fmaf(nqy[i], py, t[i]);
#pragma unroll
      for (int i = 0; i < 16; ++i) t[i] = fmaf(nqz[i], pz, t[i]);
      float m0 = fminf(fminf(t[0],  t[1]),  t[2]);
      float m1 = fminf(fminf(t[3],  t[4]),  t[5]);
      float m2 = fminf(fminf(t[6],  t[7]),  t[8]);
      float m3 = fminf(fminf(t[9],  t[10]), t[11]);
      float m4 = fminf(fminf(t[12], t[13]), t[14]);
      float r0 = fminf(fminf(m0, m1), m2);
      float r1 = fminf(fminf(m3, m4), t[15]);
      red[p][tid] = fminf(r0, r1);
    }
    __syncthreads();

    {
      const int p   = tid >> 4;
      const int sub = tid & 15;
      const float4* r4 = (const float4*)&red[p][sub * 16];
      float4 v0 = r4[0], v1 = r4[1], v2 = r4[2], v3 = r4[3];
      float w0 = fminf(fminf(v0.x, v0.y), fminf(v0.z, v0.w));
      float w1 = fminf(fminf(v1.x, v1.y), fminf(v1.z, v1.w));
      float w2 = fminf(fminf(v2.x, v2.y), fminf(v2.z, v2.w));
      float w3 = fminf(fminf(v3.x, v3.y), fminf(v3.z, v3.w));
      float v  = fminf(fminf(w0, w1), fminf(w2, w3));
#pragma unroll
      for (int o = 1; o < 16; o <<= 1) v = fminf(v, __shfl_xor(v, o));
      if (sub == 0) {
        int i = cbase + p;
        float px = pos[3*i+0], py = pos[3*i+1], pz = pos[3*i+2];
        float p2 = px*px + py*py + pz*pz;
        float d2 = fmaf(2.f, v, p2);
        d2 = fmaxf(d2, 1e-12f);
        int n = i & (N_SZ - 1);
        int b = i >> 10;
        xT[n * 64 + b] = sqrtf(d2);
      }
    }
    __syncthreads();
  }
}

// ---------------------------------------------------------------------------
// Kernel 2 (v5): K-split GEMM, 4-deep DMA ring + counted vmcnt + RAW barriers.
//   P[s][j][b] = sum_{k in slice s} xT[k][b] * W[k][j]
// Sub-chunk = 16 k-rows (4 KB); ring of 4 slots; per wave 1 DMA instr per
// sub-chunk (its 4 rows). Steady state: 4 DMAs outstanding, wait vmcnt(3)
// (NEVER 0 in-loop), raw s_barrier (no compiler drain). Two raw barriers
// per sub-chunk protect cross-wave DMA visibility and slot reuse.
// ---------------------------------------------------------------------------
template <int K, int J, int JT, int KSPAN>
__global__ __launch_bounds__(256, 2) void gemm5_kernel(
    const float* __restrict__ xT,   // [K][64]
    const float* __restrict__ W,    // [K][J]
    float* __restrict__ P)          // [K/KSPAN][J][64]
{
  constexpr int NS = KSPAN / 16;          // sub-chunks per slice (4 or 8)
  const int jt   = blockIdx.x % JT;
  const int s    = blockIdx.x / JT;
  const int tid  = threadIdx.x;
  const int lane = tid & 63;
  const int wave = tid >> 6;
  const int jl = lane & 15;
  const int bq = lane >> 4;
  const int j0 = jt * 64 + jl * 4;
  const int b0 = wave * 16 + bq * 4;

  __shared__ __align__(16) float xs[KSPAN][64];    // KSPAN*256 B
  __shared__ __align__(16) float ring[4][16][64];  // 16 KB

  // stage x slice (coalesced float4), full drain ONCE
  {
    const float4* sx = (const float4*)(xT + (size_t)s * KSPAN * 64);
    float4* dx = (float4*)&xs[0][0];
#pragma unroll
    for (int i = 0; i < KSPAN / 16; ++i)
      dx[i * 256 + tid] = sx[i * 256 + tid];
  }
  __syncthreads();   // one-time full drain; vmcnt back to 0 after this

  // W DMA source: wave w covers rows w*4..w*4+3 of each 16-row sub-chunk.
  // lane L -> row +(L>>4), col (L&15)*4; LDS dest linear base + L*16.
  const float* wbase = W + ((size_t)s * KSPAN + wave * 4 + (lane >> 4)) * J
                         + jt * 64 + (lane & 15) * 4;

  // prologue: DMA sub-chunks 0,1,2 into slots 0,1,2 (3 outstanding)
#pragma unroll
  for (int i = 0; i < 3; ++i)
    __builtin_amdgcn_global_load_lds(
        (const AS1 void*)(wbase + (size_t)(i * 16) * J),
        (AS3 void*)&ring[i][wave * 4][0], 16, 0, 0);

  float acc[4][4];
#pragma unroll
  for (int a = 0; a < 4; ++a)
#pragma unroll
    for (int c = 0; c < 4; ++c) acc[a][c] = 0.f;

#pragma unroll 1
  for (int i = 0; i < NS; ++i) {
    // issue DMA for sub-chunk i+3 (dummy wrap at tail keeps count uniform;
    // writes a slot whose consumer finished last iter, barrier-protected)
    const int nxt = (i + 3) & (NS - 1);
    __builtin_amdgcn_global_load_lds(
        (const AS1 void*)(wbase + (size_t)(nxt * 16) * J),
        (AS3 void*)&ring[(i + 3) & 3][wave * 4][0], 16, 0, 0);
    // own oldest DMA (sub-chunk i) done; raw barrier -> everyone's done
    asm volatile("s_waitcnt vmcnt(3)" ::: "memory");
    __builtin_amdgcn_s_barrier();
    __builtin_amdgcn_sched_barrier(0);
    // compute 16 k-rows from slot i&3
#pragma unroll
    for (int r = 0; r < 16; ++r) {
      float4 w4 = *(const float4*)&ring[i & 3][r][jl * 4];
      float4 x4 = *(const float4*)&xs[i * 16 + r][b0];
      const float wv[4] = {w4.x, w4.y, w4.z, w4.w};
      const float xv[4] = {x4.x, x4.y, x4.z, x4.w};
#pragma unroll
      for (int a = 0; a < 4; ++a)
#pragma unroll
        for (int c = 0; c < 4; ++c)
          acc[a][c] = fmaf(xv[a], wv[c], acc[a][c]);
    }
    // all waves done reading slot i&3 before anyone re-DMAs it next iter
    __builtin_amdgcn_s_barrier();
  }
  asm volatile("s_waitcnt vmcnt(0)" ::: "memory");  // drain dangling tail DMAs

#pragma unroll
  for (int c = 0; c < 4; ++c) {
    float4 o = make_float4(acc[0][c], acc[1][c], acc[2][c], acc[3][c]);
    *(float4*)(P + ((size_t)s * J + (j0 + c)) * 64 + b0) = o;
  }
}

// ---------------------------------------------------------------------------
// Kernel 3: reduce K-split partials + bias (+ReLU); optional transposed write.
// ---------------------------------------------------------------------------
template <int J, int KS, bool RELU, bool TRANS>
__global__ __launch_bounds__(256) void reduce_bias_kernel(
    const float* __restrict__ P, const float* __restrict__ bias,
    float* __restrict__ out)
{
  const int t = blockIdx.x * 256 + threadIdx.x;
  const int b = t & 63;
  const int j = t >> 6;
  float v = 0.f;
#pragma unroll
  for (int s = 0; s < KS; ++s) v += P[((size_t)s * J + j) * 64 + b];
  v += bias[j];
  if (RELU) v = fmaxf(v, 0.f);
  if (TRANS) out[j * 64 + b] = v;
  else       out[(size_t)b * J + j] = v;
}

// ---------------------------------------------------------------------------
// PROBE: exact inner compute loop from static LDS, 16 reps, no global traffic
// in the loop. Sized ~55us so it appears in top-5 WITH counters. If VALUBusy
// >=85% here, compute is healthy and the GEMM sink is staging; if slow, the
// FMA loop codegen itself is broken.
// ---------------------------------------------------------------------------
__global__ __launch_bounds__(256, 2) void probe_kernel(float* __restrict__ out)
{
  __shared__ __align__(16) float xs[128][64];
  __shared__ __align__(16) float wr[16][64];
  const int tid  = threadIdx.x;
  const int lane = tid & 63;
  const int wave = tid >> 6;
  const int jl = lane & 15;
  const int bq = lane >> 4;
  const int b0 = wave * 16 + bq * 4;

  for (int i = tid; i < 128 * 64; i += 256) ((float*)xs)[i] = (float)(i & 7);
  for (int i = tid; i < 16 * 64;  i += 256) ((float*)wr)[i] = (float)(i & 5);
  __syncthreads();

  float acc[4][4];
#pragma unroll
  for (int a = 0; a < 4; ++a)
#pragma unroll
    for (int c = 0; c < 4; ++c) acc[a][c] = 0.f;

#pragma unroll 1
  for (int rep = 0; rep < 16; ++rep) {
#pragma unroll 1
    for (int i = 0; i < 8; ++i) {
#pragma unroll
      for (int r = 0; r < 16; ++r) {
        float4 w4 = *(const float4*)&wr[r][jl * 4];
        float4 x4 = *(const float4*)&xs[i * 16 + r][b0];
        const float wv[4] = {w4.x, w4.y, w4.z, w4.w};
        const float xv[4] = {x4.x, x4.y, x4.z, x4.w};
#pragma unroll
        for (int a = 0; a < 4; ++a)
#pragma unroll
          for (int c = 0; c < 4; ++c)
            acc[a][c] = fmaf(xv[a], wv[c], acc[a][c]);
      }
    }
  }

  float* o = out + ((size_t)blockIdx.x * 256 + tid) * 16;
#pragma unroll
  for (int a = 0; a < 4; ++a)
#pragma unroll
    for (int c = 0; c < 4; ++c) o[a * 4 + c] = acc[a][c];
}

// ---------------------------------------------------------------------------
extern "C" void kernel_launch(void* const* d_in, const int* in_sizes, int n_in,
                              void* d_out, int out_size, void* d_ws, size_t ws_size,
                              hipStream_t stream) {
  const float* pos   = (const float*)d_in[0];
  const float* basis = (const float*)d_in[1];
  const float* W0    = (const float*)d_in[2];
  const float* b0    = (const float*)d_in[3];
  const float* W1    = (const float*)d_in[4];
  const float* b1    = (const float*)d_in[5];
  const float* W2    = (const float*)d_in[6];
  const float* b2    = (const float*)d_in[7];
  const float* W3    = (const float*)d_in[8];
  const float* b3    = (const float*)d_in[9];
  float* out = (float*)d_out;

  char* ws = (char*)d_ws;
  float* P    = (float*)ws;                                  // <= 8 MiB
  float* xA   = (float*)(ws + (8u << 20));                   // 512 KiB
  float* xB   = (float*)(ws + (8u << 20) + (512u << 10));    // 512 KiB
  float* prb  = (float*)(ws + (16u << 20));                  // 8 MiB probe out

  // 1) distances + min -> xT0 [1024][64] in xA
  dist_min_kernel<<<512, 256, 0, stream>>>(pos, basis, xA);

  // 2) layer 0: [64,1024]@[1024,2048]; KSPAN=128 -> 8 slices, 256 blocks
  gemm5_kernel<1024, HID_SZ, 32, 128><<<8 * 32, 256, 0, stream>>>(xA, W0, P);
  reduce_bias_kernel<HID_SZ, 8, true, true>
      <<<HID_SZ * 64 / 256, 256, 0, stream>>>(P, b0, xB);

  // 3) layer 1: KSPAN=128 -> 16 slices, 512 blocks
  gemm5_kernel<2048, HID_SZ, 32, 128><<<16 * 32, 256, 0, stream>>>(xB, W1, P);
  reduce_bias_kernel<HID_SZ, 16, true, true>
      <<<HID_SZ * 64 / 256, 256, 0, stream>>>(P, b1, xA);

  // 4) layer 2
  gemm5_kernel<2048, HID_SZ, 32, 128><<<16 * 32, 256, 0, stream>>>(xA, W2, P);
  reduce_bias_kernel<HID_SZ, 16, true, true>
      <<<HID_SZ * 64 / 256, 256, 0, stream>>>(P, b2, xB);

  // 5) layer 3: KSPAN=64 -> 32 slices, 256 blocks
  gemm5_kernel<2048, OUT_SZ, 8, 64><<<32 * 8, 256, 0, stream>>>(xB, W3, P);
  reduce_bias_kernel<OUT_SZ, 32, false, false>
      <<<OUT_SZ * 64 / 256, 256, 0, stream>>>(P, b3, out);

  // 6) diagnostic probe (writes to private ws region; remove once read)
  probe_kernel<<<512, 256, 0, stream>>>(prb);
}

// Round 10
// 182.814 us; speedup vs baseline: 1.4079x; 1.4079x over previous
//
#include <hip/hip_runtime.h>
#include <hip/hip_bf16.h>
#include <math.h>

// Problem constants
#define B_SZ   64
#define N_SZ   1024
#define M_SZ   4096
#define HID_SZ 2048
#define OUT_SZ 512

// ---------------------------------------------------------------------------
// Kernel 1: pairwise min-distance (unchanged; correctness-proven).
//   xT[n][b] = min_j || pos[b,n,:] - basis[j,:] ||
// ---------------------------------------------------------------------------
__global__ __launch_bounds__(256, 2) void dist_min_kernel(
    const float* __restrict__ pos,    // [B*N][3]
    const float* __restrict__ basis,  // [M][3]
    float* __restrict__ xT)           // [N][B]
{
  const int tid  = threadIdx.x;
  const int lane = tid & 63;
  const int wave = tid >> 6;

  float nqx[16], nqy[16], nqz[16], qc[16];
#pragma unroll
  for (int i = 0; i < 16; ++i) {
    int j = wave * 1024 + i * 64 + lane;
    float qx = basis[3*j+0], qy = basis[3*j+1], qz = basis[3*j+2];
    nqx[i] = -qx; nqy[i] = -qy; nqz[i] = -qz;
    qc[i]  = 0.5f * (qx*qx + qy*qy + qz*qz);
  }

  __shared__ float red[16][256];
  const int pbase = blockIdx.x * 128;

  for (int c = 0; c < 8; ++c) {
    const int cbase = pbase + c * 16;
    const float* pp = pos + (size_t)3 * cbase;
    float pc[48];
#pragma unroll
    for (int e = 0; e < 48; ++e) pc[e] = pp[e];

#pragma unroll   // FULL unroll (rule #20)
    for (int p = 0; p < 16; ++p) {
      const float px = pc[3*p+0], py = pc[3*p+1], pz = pc[3*p+2];
      float t[16];
#pragma unroll
      for (int i = 0; i < 16; ++i) t[i] = fmaf(nqx[i], px, qc[i]);
#pragma unroll
      for (int i = 0; i < 16; ++i) t[i] = fmaf(nqy[i], py, t[i]);
#pragma unroll
      for (int i = 0; i < 16; ++i) t[i] = fmaf(nqz[i], pz, t[i]);
      float m0 = fminf(fminf(t[0],  t[1]),  t[2]);
      float m1 = fminf(fminf(t[3],  t[4]),  t[5]);
      float m2 = fminf(fminf(t[6],  t[7]),  t[8]);
      float m3 = fminf(fminf(t[9],  t[10]), t[11]);
      float m4 = fminf(fminf(t[12], t[13]), t[14]);
      float r0 = fminf(fminf(m0, m1), m2);
      float r1 = fminf(fminf(m3, m4), t[15]);
      red[p][tid] = fminf(r0, r1);
    }
    __syncthreads();

    {
      const int p   = tid >> 4;
      const int sub = tid & 15;
      const float4* r4 = (const float4*)&red[p][sub * 16];
      float4 v0 = r4[0], v1 = r4[1], v2 = r4[2], v3 = r4[3];
      float w0 = fminf(fminf(v0.x, v0.y), fminf(v0.z, v0.w));
      float w1 = fminf(fminf(v1.x, v1.y), fminf(v1.z, v1.w));
      float w2 = fminf(fminf(v2.x, v2.y), fminf(v2.z, v2.w));
      float w3 = fminf(fminf(v3.x, v3.y), fminf(v3.z, v3.w));
      float v  = fminf(fminf(w0, w1), fminf(w2, w3));
#pragma unroll
      for (int o = 1; o < 16; o <<= 1) v = fminf(v, __shfl_xor(v, o));
      if (sub == 0) {
        int i = cbase + p;
        float px = pos[3*i+0], py = pos[3*i+1], pz = pos[3*i+2];
        float p2 = px*px + py*py + pz*pz;
        float d2 = fmaf(2.f, v, p2);
        d2 = fmaxf(d2, 1e-12f);
        int n = i & (N_SZ - 1);
        int b = i >> 10;
        xT[n * 64 + b] = sqrtf(d2);
      }
    }
    __syncthreads();
  }
}

// ---------------------------------------------------------------------------
// Kernel 2 (v6): K-split GEMM, register-pipelined W, ZERO barriers in K-loop.
//   P[s][j][b] = sum_{k in slice s} xT[k][b] * W[k][j]
// Probe (r8) proved the LDS-broadcast x + 16-FMA loop runs at ~94 TF; every
// LDS-ring W variant stalled on its vmcnt/barrier machinery. So W now goes
// straight to registers: two 8-deep float4 batches (64 VGPR), 128 FMA
// between compiler-emitted COUNTED vmcnt waits; waves fully independent
// after the one-time x stage. Each lane loads exactly the W floats it
// consumes (quad-duplicate addresses coalesce to one 256B line per row).
// ~120 VGPR at launch_bounds(256,2) (cap 256): no spill, 2 blocks/CU.
// ---------------------------------------------------------------------------
template <int K, int J, int JT, int KSPAN>
__global__ __launch_bounds__(256, 2) void gemm6_kernel(
    const float* __restrict__ xT,   // [K][64]
    const float* __restrict__ W,    // [K][J]
    float* __restrict__ P)          // [K/KSPAN][J][64]
{
  const int jt   = blockIdx.x % JT;
  const int s    = blockIdx.x / JT;
  const int tid  = threadIdx.x;
  const int lane = tid & 63;
  const int wave = tid >> 6;
  const int jl = lane & 15;
  const int bq = lane >> 4;
  const int j0 = jt * 64 + jl * 4;
  const int b0 = wave * 16 + bq * 4;

  __shared__ __align__(16) float xs[KSPAN][64];   // KSPAN*256 B

  // stage x slice (coalesced float4), one-time barrier
  {
    const float4* sx = (const float4*)(xT + (size_t)s * KSPAN * 64);
    float4* dx = (float4*)&xs[0][0];
#pragma unroll
    for (int i = 0; i < KSPAN / 16; ++i)
      dx[i * 256 + tid] = sx[i * 256 + tid];
  }
  __syncthreads();

  // per-thread W column base (quad-duplicated addresses coalesce)
  const float* wq = W + (size_t)s * KSPAN * J + j0;

  float acc[4][4];
#pragma unroll
  for (int a = 0; a < 4; ++a)
#pragma unroll
    for (int c = 0; c < 4; ++c) acc[a][c] = 0.f;

  float4 A[8], Bf[8];

  // prologue: batch A <- rows 0..7 (8 independent loads in flight)
#pragma unroll
  for (int u = 0; u < 8; ++u)
    A[u] = *(const float4*)(wq + (size_t)u * J);

#pragma unroll 1
  for (int kk = 0; kk < KSPAN; kk += 16) {
    // issue batch B <- rows kk+8..kk+15
#pragma unroll
    for (int u = 0; u < 8; ++u)
      Bf[u] = *(const float4*)(wq + (size_t)(kk + 8 + u) * J);
    // compute batch A (compiler emits counted vmcnt: waits only A's loads)
#pragma unroll
    for (int u = 0; u < 8; ++u) {
      float4 x4 = *(const float4*)&xs[kk + u][b0];
      const float wv[4] = {A[u].x, A[u].y, A[u].z, A[u].w};
      const float xv[4] = {x4.x, x4.y, x4.z, x4.w};
#pragma unroll
      for (int a = 0; a < 4; ++a)
#pragma unroll
        for (int c = 0; c < 4; ++c)
          acc[a][c] = fmaf(xv[a], wv[c], acc[a][c]);
    }
    // issue next batch A <- rows kk+16..kk+23 (guarded, uniform)
    if (kk + 16 < KSPAN) {
#pragma unroll
      for (int u = 0; u < 8; ++u)
        A[u] = *(const float4*)(wq + (size_t)(kk + 16 + u) * J);
    }
    // compute batch B
#pragma unroll
    for (int u = 0; u < 8; ++u) {
      float4 x4 = *(const float4*)&xs[kk + 8 + u][b0];
      const float wv[4] = {Bf[u].x, Bf[u].y, Bf[u].z, Bf[u].w};
      const float xv[4] = {x4.x, x4.y, x4.z, x4.w};
#pragma unroll
      for (int a = 0; a < 4; ++a)
#pragma unroll
        for (int c = 0; c < 4; ++c)
          acc[a][c] = fmaf(xv[a], wv[c], acc[a][c]);
    }
  }

#pragma unroll
  for (int c = 0; c < 4; ++c) {
    float4 o = make_float4(acc[0][c], acc[1][c], acc[2][c], acc[3][c]);
    *(float4*)(P + ((size_t)s * J + (j0 + c)) * 64 + b0) = o;
  }
}

// ---------------------------------------------------------------------------
// Kernel 3: reduce K-split partials + bias (+ReLU); optional transposed write.
// ---------------------------------------------------------------------------
template <int J, int KS, bool RELU, bool TRANS>
__global__ __launch_bounds__(256) void reduce_bias_kernel(
    const float* __restrict__ P, const float* __restrict__ bias,
    float* __restrict__ out)
{
  const int t = blockIdx.x * 256 + threadIdx.x;
  const int b = t & 63;
  const int j = t >> 6;
  float v = 0.f;
#pragma unroll
  for (int s = 0; s < KS; ++s) v += P[((size_t)s * J + j) * 64 + b];
  v += bias[j];
  if (RELU) v = fmaxf(v, 0.f);
  if (TRANS) out[j * 64 + b] = v;
  else       out[(size_t)b * J + j] = v;
}

// ---------------------------------------------------------------------------
extern "C" void kernel_launch(void* const* d_in, const int* in_sizes, int n_in,
                              void* d_out, int out_size, void* d_ws, size_t ws_size,
                              hipStream_t stream) {
  const float* pos   = (const float*)d_in[0];
  const float* basis = (const float*)d_in[1];
  const float* W0    = (const float*)d_in[2];
  const float* b0    = (const float*)d_in[3];
  const float* W1    = (const float*)d_in[4];
  const float* b1    = (const float*)d_in[5];
  const float* W2    = (const float*)d_in[6];
  const float* b2    = (const float*)d_in[7];
  const float* W3    = (const float*)d_in[8];
  const float* b3    = (const float*)d_in[9];
  float* out = (float*)d_out;

  char* ws = (char*)d_ws;
  float* P  = (float*)ws;                                  // <= 8 MiB
  float* xA = (float*)(ws + (8u << 20));                   // 512 KiB
  float* xB = (float*)(ws + (8u << 20) + (512u << 10));    // 512 KiB

  // 1) distances + min -> xT0 [1024][64] in xA
  dist_min_kernel<<<512, 256, 0, stream>>>(pos, basis, xA);

  // 2) layer 0: [64,1024]@[1024,2048]; KSPAN=128 -> 8 slices x 32 jt
  gemm6_kernel<1024, HID_SZ, 32, 128><<<8 * 32, 256, 0, stream>>>(xA, W0, P);
  reduce_bias_kernel<HID_SZ, 8, true, true>
      <<<HID_SZ * 64 / 256, 256, 0, stream>>>(P, b0, xB);

  // 3) layer 1: [64,2048]@[2048,2048]; KSPAN=128 -> 16 slices x 32 jt
  gemm6_kernel<2048, HID_SZ, 32, 128><<<16 * 32, 256, 0, stream>>>(xB, W1, P);
  reduce_bias_kernel<HID_SZ, 16, true, true>
      <<<HID_SZ * 64 / 256, 256, 0, stream>>>(P, b1, xA);

  // 4) layer 2
  gemm6_kernel<2048, HID_SZ, 32, 128><<<16 * 32, 256, 0, stream>>>(xA, W2, P);
  reduce_bias_kernel<HID_SZ, 16, true, true>
      <<<HID_SZ * 64 / 256, 256, 0, stream>>>(P, b2, xB);

  // 5) layer 3: [64,2048]@[2048,512]; KSPAN=64 -> 32 slices x 8 jt
  gemm6_kernel<2048, OUT_SZ, 8, 64><<<32 * 8, 256, 0, stream>>>(xB, W3, P);
  reduce_bias_kernel<OUT_SZ, 32, false, false>
      <<<OUT_SZ * 64 / 256, 256, 0, stream>>>(P, b3, out);
}